// Round 1
// baseline (16447.423 us; speedup 1.0000x reference)
//
#include <hip/hip_runtime.h>

// ---- model constants ----
#define T_SEQ  1024
#define NH     12
#define CDIM   768
#define HDIM   64
#define NLAYER 12
#define VOCAB  50257
#define BROWS  2048   // B*T

typedef __attribute__((ext_vector_type(8))) short  short8;
typedef __attribute__((ext_vector_type(4))) float  f32x4;

__device__ __forceinline__ unsigned short f2bf(float f) {
    unsigned int u = __float_as_uint(f);
    u += 0x7fffu + ((u >> 16) & 1u);          // round-to-nearest-even
    return (unsigned short)(u >> 16);
}

// ---------------------------------------------------------------------------
// FIRE bias: bias[i][j] = MLP(log(c*(i-j)+1)/log(c*i+1)) for j<=i else -1e30
// ---------------------------------------------------------------------------
__global__ __launch_bounds__(256) void fire_kernel(
    const float* __restrict__ log_c,
    const float* __restrict__ v1w, const float* __restrict__ v1b,
    const float* __restrict__ v2w, const float* __restrict__ v2b,
    const float* __restrict__ v3w, const float* __restrict__ v3b,
    float* __restrict__ bias)
{
    int gid = blockIdx.x * 256 + threadIdx.x;
    int i = gid >> 10, j = gid & 1023;
    if (j > i) { bias[gid] = -1e30f; return; }
    float c  = expf(log_c[0]);
    float fi = (float)(i + 1), fj = (float)(j + 1);
    float pv = logf(c * (fi - fj) + 1.0f) / logf(c * fi + 1.0f);
    float h1[32];
#pragma unroll
    for (int k = 0; k < 32; ++k) {
        float t = pv * v1w[k] + v1b[k];
        h1[k] = t > 0.0f ? t : 0.0f;
    }
    float fire = v3b[0];
#pragma unroll 4
    for (int k2 = 0; k2 < 32; ++k2) {
        float t = v2b[k2];
#pragma unroll
        for (int k1 = 0; k1 < 32; ++k1) t += h1[k1] * v2w[k1 * 32 + k2];
        fire += (t > 0.0f ? t : 0.0f) * v3w[k2];
    }
    bias[gid] = fire;
}

// ---------------------------------------------------------------------------
// Embedding gather: x[b,t,:] = wte[idx[b,t],:]
// ---------------------------------------------------------------------------
__global__ __launch_bounds__(256) void embed_kernel(
    const int* __restrict__ idx, const float* __restrict__ wte,
    float* __restrict__ x)
{
    int t = blockIdx.x;
    int tok = idx[t];
    const float* src = wte + (size_t)tok * CDIM;
    float* dst = x + (size_t)t * CDIM;
    for (int c = threadIdx.x; c < CDIM; c += 256) dst[c] = src[c];
}

// ---------------------------------------------------------------------------
// LayerNorm (C=768): f32 in -> bf16 out. One block per row, 3 elems/thread.
// ---------------------------------------------------------------------------
__global__ __launch_bounds__(256) void ln_kernel(
    const float* __restrict__ x, const float* __restrict__ g,
    const float* __restrict__ b, unsigned short* __restrict__ out)
{
    int row = blockIdx.x, tid = threadIdx.x;
    const float* xr = x + (size_t)row * CDIM;
    float v0 = xr[tid], v1 = xr[tid + 256], v2 = xr[tid + 512];
    float s = v0 + v1 + v2;
    float q = v0 * v0 + v1 * v1 + v2 * v2;
#pragma unroll
    for (int o = 32; o > 0; o >>= 1) { s += __shfl_down(s, o); q += __shfl_down(q, o); }
    __shared__ float red[8];
    __shared__ float stat[2];
    int lane = tid & 63, wid = tid >> 6;
    if (lane == 0) { red[wid] = s; red[4 + wid] = q; }
    __syncthreads();
    if (tid == 0) {
        float S = red[0] + red[1] + red[2] + red[3];
        float Q = red[4] + red[5] + red[6] + red[7];
        float m = S * (1.0f / CDIM);
        float var = Q * (1.0f / CDIM) - m * m;
        stat[0] = m; stat[1] = rsqrtf(var + 1e-5f);
    }
    __syncthreads();
    float m = stat[0], r = stat[1];
    unsigned short* orow = out + (size_t)row * CDIM;
    orow[tid      ] = f2bf((v0 - m) * r * g[tid      ] + b[tid      ]);
    orow[tid + 256] = f2bf((v1 - m) * r * g[tid + 256] + b[tid + 256]);
    orow[tid + 512] = f2bf((v2 - m) * r * g[tid + 512] + b[tid + 512]);
}

// ---------------------------------------------------------------------------
// bf16 MFMA GEMM: out[M,N] = epi(A[M,K]bf16 @ B + bias, resid)
//   BT=false: B is (K,N) f32 row-major (converted to bf16 during staging)
//   BT=true : B is (N,K) f32 row-major (wte for tied lm_head)
//   EPI: 0 = (+bias), 1 = gelu(+bias), 2 = resid + (+bias)
// 64x64 tile, 4 waves (2x2), each wave 32x32 via 2x2 mfma_f32_16x16x32_bf16.
// Fragment layout (HW-verified): A/B frag elem j = [row|col=lane&15][k=(lane>>4)*8+j]
//                                 C/D: col=lane&15, row=(lane>>4)*4+reg
// Requires: M%64==0, K%32==0; N%64==0 unless BT (col-guarded).
// ---------------------------------------------------------------------------
template <int EPI, bool BT, typename OT>
__global__ __launch_bounds__(256) void gemm_kernel(
    const unsigned short* __restrict__ A, const float* __restrict__ B,
    const float* __restrict__ bias, const float* __restrict__ resid,
    OT* __restrict__ out, int M, int N, int K)
{
    __shared__ unsigned short As[64][40];   // [m][k], stride 40 avoids pow2 conflicts
    __shared__ unsigned short Bs[64][40];   // [n][k] (B transposed in LDS)

    int tid  = threadIdx.x;
    int lane = tid & 63, wid = tid >> 6;
    int wRow = (wid >> 1) * 32, wCol = (wid & 1) * 32;
    int fr = lane & 15, fg = lane >> 4;
    int tRow = blockIdx.y * 64, tCol = blockIdx.x * 64;

    f32x4 acc[2][2];
#pragma unroll
    for (int mi = 0; mi < 2; ++mi)
#pragma unroll
        for (int ni = 0; ni < 2; ++ni)
            acc[mi][ni] = (f32x4){0.f, 0.f, 0.f, 0.f};

    int ar = tid >> 2, ac = (tid & 3) * 8;          // A staging: 8 bf16 per thread

    for (int k0 = 0; k0 < K; k0 += 32) {
        // ---- stage A (bf16 -> bf16, vectorized 16B) ----
        *(short8*)&As[ar][ac] =
            *(const short8*)(A + (size_t)(tRow + ar) * K + k0 + ac);
        // ---- stage B transposed (f32 -> bf16) ----
        if (BT) {
            int bn = tid >> 2, bk = (tid & 3) * 8;
            int gn = tCol + bn;
            float4 w0 = {0,0,0,0}, w1 = {0,0,0,0};
            if (gn < N) {
                const float* gb = B + (size_t)gn * K + k0 + bk;
                w0 = *(const float4*)gb;
                w1 = *(const float4*)(gb + 4);
            }
            unsigned short* dst = &Bs[bn][bk];
            dst[0] = f2bf(w0.x); dst[1] = f2bf(w0.y); dst[2] = f2bf(w0.z); dst[3] = f2bf(w0.w);
            dst[4] = f2bf(w1.x); dst[5] = f2bf(w1.y); dst[6] = f2bf(w1.z); dst[7] = f2bf(w1.w);
        } else {
            int bk = tid & 31, bn = (tid >> 5) * 8;
            const float* gb = B + (size_t)(k0 + bk) * N + tCol + bn;
            float4 w0 = *(const float4*)gb;
            float4 w1 = *(const float4*)(gb + 4);
            Bs[bn + 0][bk] = f2bf(w0.x); Bs[bn + 1][bk] = f2bf(w0.y);
            Bs[bn + 2][bk] = f2bf(w0.z); Bs[bn + 3][bk] = f2bf(w0.w);
            Bs[bn + 4][bk] = f2bf(w1.x); Bs[bn + 5][bk] = f2bf(w1.y);
            Bs[bn + 6][bk] = f2bf(w1.z); Bs[bn + 7][bk] = f2bf(w1.w);
        }
        __syncthreads();

        short8 af[2], bf_[2];
#pragma unroll
        for (int mi = 0; mi < 2; ++mi)
            af[mi] = *(const short8*)&As[wRow + mi * 16 + fr][fg * 8];
#pragma unroll
        for (int ni = 0; ni < 2; ++ni)
            bf_[ni] = *(const short8*)&Bs[wCol + ni * 16 + fr][fg * 8];
#pragma unroll
        for (int mi = 0; mi < 2; ++mi)
#pragma unroll
            for (int ni = 0; ni < 2; ++ni)
                acc[mi][ni] = __builtin_amdgcn_mfma_f32_16x16x32_bf16(
                    af[mi], bf_[ni], acc[mi][ni], 0, 0, 0);
        __syncthreads();
    }

    // ---- epilogue ----
#pragma unroll
    for (int mi = 0; mi < 2; ++mi) {
#pragma unroll
        for (int ni = 0; ni < 2; ++ni) {
            int ocol = tCol + wCol + ni * 16 + fr;
            if (ocol >= N) continue;
            float bv = bias ? bias[ocol] : 0.0f;
#pragma unroll
            for (int i = 0; i < 4; ++i) {
                int orow = tRow + wRow + mi * 16 + fg * 4 + i;
                float v = acc[mi][ni][i] + bv;
                if (EPI == 1) {
                    float t = v;
                    v = 0.5f * t * (1.0f + tanhf(0.7978845608028654f *
                                                 (t + 0.044715f * t * t * t)));
                }
                size_t oidx = (size_t)orow * N + ocol;
                if (EPI == 2) v += resid[oidx];
                if constexpr (sizeof(OT) == 4) out[oidx] = v;
                else                           out[oidx] = (OT)f2bf(v);
            }
        }
    }
}

// ---------------------------------------------------------------------------
// Attention: one block per (b, h, query-row i). f32 VALU (tiny FLOP share).
// qkv layout: [b,t, 3C] with q at +0, k at +C, v at +2C; head h spans h*64..
// Writes y as bf16 in (B,T,C) layout.
// ---------------------------------------------------------------------------
__global__ __launch_bounds__(256) void attn_kernel(
    const float* __restrict__ qkv, const float* __restrict__ bias,
    unsigned short* __restrict__ y)
{
    int rid = blockIdx.x;
    int i = rid & (T_SEQ - 1);
    int h = (rid >> 10) % NH;
    int b = rid / (NH * T_SEQ);
    const int THREE = 3 * CDIM;
    const float scale = 0.125f;  // 1/sqrt(64)

    __shared__ float qs[HDIM];
    __shared__ float p[T_SEQ];
    __shared__ float red[8];
    __shared__ float part[4][HDIM];

    int tid = threadIdx.x, lane = tid & 63, wid = tid >> 6;

    const float* qrow = qkv + ((size_t)(b * T_SEQ + i)) * THREE + h * HDIM;
    if (tid < HDIM) qs[tid] = qrow[tid] * scale;
    __syncthreads();

    const float* kbase = qkv + (size_t)b * T_SEQ * THREE + CDIM + h * HDIM;
    const float* brow  = bias + (size_t)i * T_SEQ;

    float lmax = -1e30f;
    for (int j = tid; j < T_SEQ; j += 256) {
        float s;
        if (j <= i) {
            const float4* kr = (const float4*)(kbase + (size_t)j * THREE);
            float d = 0.0f;
#pragma unroll
            for (int q8 = 0; q8 < 16; ++q8) {
                float4 kv = kr[q8];
                d += qs[q8 * 4] * kv.x + qs[q8 * 4 + 1] * kv.y +
                     qs[q8 * 4 + 2] * kv.z + qs[q8 * 4 + 3] * kv.w;
            }
            s = d + brow[j];
        } else {
            s = -1e30f;
        }
        p[j] = s;
        lmax = fmaxf(lmax, s);
    }
#pragma unroll
    for (int o = 32; o > 0; o >>= 1) lmax = fmaxf(lmax, __shfl_down(lmax, o));
    if (lane == 0) red[wid] = lmax;
    __syncthreads();
    float m = fmaxf(fmaxf(red[0], red[1]), fmaxf(red[2], red[3]));

    float lsum = 0.0f;
    for (int j = tid; j < T_SEQ; j += 256) {
        float e = expf(p[j] - m);
        p[j] = e;
        lsum += e;
    }
#pragma unroll
    for (int o = 32; o > 0; o >>= 1) lsum += __shfl_down(lsum, o);
    if (lane == 0) red[4 + wid] = lsum;
    __syncthreads();
    float rinv = 1.0f / (red[4] + red[5] + red[6] + red[7]);

    // PV: group g of 64 threads handles j in [g*256, (g+1)*256) ∩ [0, i]
    const float* vbase = qkv + (size_t)b * T_SEQ * THREE + 2 * CDIM + h * HDIM;
    int d = tid & 63, grp = tid >> 6;
    float acc = 0.0f;
    int jhi = min((grp + 1) * 256, i + 1);
    for (int j = grp * 256; j < jhi; ++j)
        acc += p[j] * vbase[(size_t)j * THREE + d];
    part[grp][d] = acc;
    __syncthreads();
    if (tid < HDIM) {
        float v = (part[0][tid] + part[1][tid] + part[2][tid] + part[3][tid]) * rinv;
        y[((size_t)(b * T_SEQ + i)) * CDIM + h * HDIM + tid] = f2bf(v);
    }
}

// ---------------------------------------------------------------------------
// kernel_launch
// ---------------------------------------------------------------------------
extern "C" void kernel_launch(void* const* d_in, const int* in_sizes, int n_in,
                              void* d_out, int out_size, void* d_ws, size_t ws_size,
                              hipStream_t stream)
{
    const int*   idx   = (const int*)  d_in[0];
    // d_in[1] = n_head (constant 12, hardcoded)
    const float* wte   = (const float*)d_in[2];
    const float* log_c = (const float*)d_in[3];
    const float* v1w   = (const float*)d_in[4];
    const float* v1b   = (const float*)d_in[5];
    const float* v2w   = (const float*)d_in[6];
    const float* v2b   = (const float*)d_in[7];
    const float* v3w   = (const float*)d_in[8];
    const float* v3b   = (const float*)d_in[9];
    const float* ln1g  = (const float*)d_in[10];
    const float* ln1b  = (const float*)d_in[11];
    const float* attnw = (const float*)d_in[12];
    const float* attnb = (const float*)d_in[13];
    const float* projw = (const float*)d_in[14];
    const float* projb = (const float*)d_in[15];
    const float* ln2g  = (const float*)d_in[16];
    const float* ln2b  = (const float*)d_in[17];
    const float* fcw   = (const float*)d_in[18];
    const float* fcb   = (const float*)d_in[19];
    const float* fc2w  = (const float*)d_in[20];
    const float* fc2b  = (const float*)d_in[21];
    const float* lnfg  = (const float*)d_in[22];
    const float* lnfb  = (const float*)d_in[23];
    float* outp = (float*)d_out;

    // ---- workspace layout (all sizes 256B-aligned), total ~48.2 MB ----
    char* w = (char*)d_ws;
    float* bias          = (float*)w;          w += (size_t)T_SEQ * T_SEQ * 4;     // 4 MB
    float* x             = (float*)w;          w += (size_t)BROWS * CDIM * 4;      // 6.3 MB
    unsigned short* hbuf = (unsigned short*)w; w += (size_t)BROWS * CDIM * 2;      // 3.1 MB
    float* qkv           = (float*)w;          w += (size_t)BROWS * 3 * CDIM * 4;  // 18.9 MB
    unsigned short* ybuf = (unsigned short*)w; w += (size_t)BROWS * CDIM * 2;      // 3.1 MB
    unsigned short* gbuf = (unsigned short*)w; w += (size_t)BROWS * 4 * CDIM * 2;  // 12.6 MB

    fire_kernel<<<(T_SEQ * T_SEQ) / 256, 256, 0, stream>>>(
        log_c, v1w, v1b, v2w, v2b, v3w, v3b, bias);
    embed_kernel<<<BROWS, 256, 0, stream>>>(idx, wte, x);

    for (int l = 0; l < NLAYER; ++l) {
        ln_kernel<<<BROWS, 256, 0, stream>>>(x, ln1g + l * CDIM, ln1b + l * CDIM, hbuf);
        gemm_kernel<0, false, float><<<dim3(3 * CDIM / 64, BROWS / 64), 256, 0, stream>>>(
            hbuf, attnw + (size_t)l * CDIM * 3 * CDIM, attnb + (size_t)l * 3 * CDIM,
            nullptr, qkv, BROWS, 3 * CDIM, CDIM);
        attn_kernel<<<2 * NH * T_SEQ, 256, 0, stream>>>(qkv, bias, ybuf);
        gemm_kernel<2, false, float><<<dim3(CDIM / 64, BROWS / 64), 256, 0, stream>>>(
            ybuf, projw + (size_t)l * CDIM * CDIM, projb + (size_t)l * CDIM,
            x, x, BROWS, CDIM, CDIM);
        ln_kernel<<<BROWS, 256, 0, stream>>>(x, ln2g + l * CDIM, ln2b + l * CDIM, hbuf);
        gemm_kernel<1, false, unsigned short><<<dim3(4 * CDIM / 64, BROWS / 64), 256, 0, stream>>>(
            hbuf, fcw + (size_t)l * CDIM * 4 * CDIM, fcb + (size_t)l * 4 * CDIM,
            nullptr, gbuf, BROWS, 4 * CDIM, CDIM);
        gemm_kernel<2, false, float><<<dim3(CDIM / 64, BROWS / 64), 256, 0, stream>>>(
            gbuf, fc2w + (size_t)l * 4 * CDIM * CDIM, fc2b + (size_t)l * CDIM,
            x, x, BROWS, CDIM, 4 * CDIM);
    }

    ln_kernel<<<BROWS, 256, 0, stream>>>(x, lnfg, lnfb, hbuf);
    gemm_kernel<0, true, float><<<dim3((VOCAB + 63) / 64, BROWS / 64), 256, 0, stream>>>(
        hbuf, wte, nullptr, nullptr, outp, BROWS, VOCAB, CDIM);
}

// Round 2
// 4496.457 us; speedup vs baseline: 3.6579x; 3.6579x over previous
//
#include <hip/hip_runtime.h>

// ---- model constants ----
#define T_SEQ  1024
#define NH     12
#define CDIM   768
#define HDIM   64
#define NLAYER 12
#define VOCAB  50257
#define BROWS  2048   // B*T
#define NBH    24     // B*NH
#define QKE    (NBH * T_SEQ * HDIM)   // elems per Q/K/V bf16 buffer

typedef __attribute__((ext_vector_type(8))) short  short8;
typedef __attribute__((ext_vector_type(4))) float  f32x4;

__device__ __forceinline__ unsigned short f2bf(float f) {
    unsigned int u = __float_as_uint(f);
    u += 0x7fffu + ((u >> 16) & 1u);          // round-to-nearest-even
    return (unsigned short)(u >> 16);
}

// ---------------------------------------------------------------------------
// FIRE bias: bias[i][j] = MLP(log(c*(i-j)+1)/log(c*i+1)) for j<=i else -1e30
// ---------------------------------------------------------------------------
__global__ __launch_bounds__(256) void fire_kernel(
    const float* __restrict__ log_c,
    const float* __restrict__ v1w, const float* __restrict__ v1b,
    const float* __restrict__ v2w, const float* __restrict__ v2b,
    const float* __restrict__ v3w, const float* __restrict__ v3b,
    float* __restrict__ bias)
{
    int gid = blockIdx.x * 256 + threadIdx.x;
    int i = gid >> 10, j = gid & 1023;
    if (j > i) { bias[gid] = -1e30f; return; }
    float c  = expf(log_c[0]);
    float fi = (float)(i + 1), fj = (float)(j + 1);
    float pv = logf(c * (fi - fj) + 1.0f) / logf(c * fi + 1.0f);
    float h1[32];
#pragma unroll
    for (int k = 0; k < 32; ++k) {
        float t = pv * v1w[k] + v1b[k];
        h1[k] = t > 0.0f ? t : 0.0f;
    }
    float fire = v3b[0];
#pragma unroll 4
    for (int k2 = 0; k2 < 32; ++k2) {
        float t = v2b[k2];
#pragma unroll
        for (int k1 = 0; k1 < 32; ++k1) t += h1[k1] * v2w[k1 * 32 + k2];
        fire += (t > 0.0f ? t : 0.0f) * v3w[k2];
    }
    bias[gid] = fire;
}

// ---------------------------------------------------------------------------
// Embedding gather: x[b,t,:] = wte[idx[b,t],:]
// ---------------------------------------------------------------------------
__global__ __launch_bounds__(256) void embed_kernel(
    const int* __restrict__ idx, const float* __restrict__ wte,
    float* __restrict__ x)
{
    int t = blockIdx.x;
    int tok = idx[t];
    const float* src = wte + (size_t)tok * CDIM;
    float* dst = x + (size_t)t * CDIM;
    for (int c = threadIdx.x; c < CDIM; c += 256) dst[c] = src[c];
}

// ---------------------------------------------------------------------------
// LayerNorm (C=768): f32 in -> bf16 out. One block per row, 3 elems/thread.
// ---------------------------------------------------------------------------
__global__ __launch_bounds__(256) void ln_kernel(
    const float* __restrict__ x, const float* __restrict__ g,
    const float* __restrict__ b, unsigned short* __restrict__ out)
{
    int row = blockIdx.x, tid = threadIdx.x;
    const float* xr = x + (size_t)row * CDIM;
    float v0 = xr[tid], v1 = xr[tid + 256], v2 = xr[tid + 512];
    float s = v0 + v1 + v2;
    float q = v0 * v0 + v1 * v1 + v2 * v2;
#pragma unroll
    for (int o = 32; o > 0; o >>= 1) { s += __shfl_down(s, o); q += __shfl_down(q, o); }
    __shared__ float red[8];
    __shared__ float stat[2];
    int lane = tid & 63, wid = tid >> 6;
    if (lane == 0) { red[wid] = s; red[4 + wid] = q; }
    __syncthreads();
    if (tid == 0) {
        float S = red[0] + red[1] + red[2] + red[3];
        float Q = red[4] + red[5] + red[6] + red[7];
        float m = S * (1.0f / CDIM);
        float var = Q * (1.0f / CDIM) - m * m;
        stat[0] = m; stat[1] = rsqrtf(var + 1e-5f);
    }
    __syncthreads();
    float m = stat[0], r = stat[1];
    unsigned short* orow = out + (size_t)row * CDIM;
    orow[tid      ] = f2bf((v0 - m) * r * g[tid      ] + b[tid      ]);
    orow[tid + 256] = f2bf((v1 - m) * r * g[tid + 256] + b[tid + 256]);
    orow[tid + 512] = f2bf((v2 - m) * r * g[tid + 512] + b[tid + 512]);
}

// ---------------------------------------------------------------------------
// bf16 MFMA GEMM: out[M,N] = epi(A[M,K]bf16 @ B + bias, resid)
//   BT=false: B is (K,N) f32 row-major (converted to bf16 during staging)
//   BT=true : B is (N,K) f32 row-major (wte for tied lm_head)
//   EPI: 0 = (+bias), 1 = gelu(+bias), 2 = resid + (+bias),
//        3 = scatter qkv -> Qb (x0.125) | Kb | Vt bf16 head-major buffers
// 64x64 tile, 4 waves (2x2), each wave 32x32 via 2x2 mfma_f32_16x16x32_bf16.
// Fragment layout (HW-verified): A/B frag elem j = [row|col=lane&15][k=(lane>>4)*8+j]
//                                 C/D: col=lane&15, row=(lane>>4)*4+reg
// ---------------------------------------------------------------------------
template <int EPI, bool BT, typename OT>
__global__ __launch_bounds__(256) void gemm_kernel(
    const unsigned short* __restrict__ A, const float* __restrict__ B,
    const float* __restrict__ bias, const float* __restrict__ resid,
    OT* __restrict__ out, int M, int N, int K)
{
    __shared__ unsigned short As[64][40];   // [m][k]
    __shared__ unsigned short Bs[64][40];   // [n][k] (B transposed in LDS)

    int tid  = threadIdx.x;
    int lane = tid & 63, wid = tid >> 6;
    int wRow = (wid >> 1) * 32, wCol = (wid & 1) * 32;
    int fr = lane & 15, fg = lane >> 4;
    int tRow = blockIdx.y * 64, tCol = blockIdx.x * 64;

    f32x4 acc[2][2];
#pragma unroll
    for (int mi = 0; mi < 2; ++mi)
#pragma unroll
        for (int ni = 0; ni < 2; ++ni)
            acc[mi][ni] = (f32x4){0.f, 0.f, 0.f, 0.f};

    int ar = tid >> 2, ac = (tid & 3) * 8;

    for (int k0 = 0; k0 < K; k0 += 32) {
        *(short8*)&As[ar][ac] =
            *(const short8*)(A + (size_t)(tRow + ar) * K + k0 + ac);
        if (BT) {
            int bn = tid >> 2, bk = (tid & 3) * 8;
            int gn = tCol + bn;
            float4 w0 = {0,0,0,0}, w1 = {0,0,0,0};
            if (gn < N) {
                const float* gb = B + (size_t)gn * K + k0 + bk;
                w0 = *(const float4*)gb;
                w1 = *(const float4*)(gb + 4);
            }
            unsigned short* dst = &Bs[bn][bk];
            dst[0] = f2bf(w0.x); dst[1] = f2bf(w0.y); dst[2] = f2bf(w0.z); dst[3] = f2bf(w0.w);
            dst[4] = f2bf(w1.x); dst[5] = f2bf(w1.y); dst[6] = f2bf(w1.z); dst[7] = f2bf(w1.w);
        } else {
            int bk = tid & 31, bn = (tid >> 5) * 8;
            const float* gb = B + (size_t)(k0 + bk) * N + tCol + bn;
            float4 w0 = *(const float4*)gb;
            float4 w1 = *(const float4*)(gb + 4);
            Bs[bn + 0][bk] = f2bf(w0.x); Bs[bn + 1][bk] = f2bf(w0.y);
            Bs[bn + 2][bk] = f2bf(w0.z); Bs[bn + 3][bk] = f2bf(w0.w);
            Bs[bn + 4][bk] = f2bf(w1.x); Bs[bn + 5][bk] = f2bf(w1.y);
            Bs[bn + 6][bk] = f2bf(w1.z); Bs[bn + 7][bk] = f2bf(w1.w);
        }
        __syncthreads();

        short8 af[2], bf_[2];
#pragma unroll
        for (int mi = 0; mi < 2; ++mi)
            af[mi] = *(const short8*)&As[wRow + mi * 16 + fr][fg * 8];
#pragma unroll
        for (int ni = 0; ni < 2; ++ni)
            bf_[ni] = *(const short8*)&Bs[wCol + ni * 16 + fr][fg * 8];
#pragma unroll
        for (int mi = 0; mi < 2; ++mi)
#pragma unroll
            for (int ni = 0; ni < 2; ++ni)
                acc[mi][ni] = __builtin_amdgcn_mfma_f32_16x16x32_bf16(
                    af[mi], bf_[ni], acc[mi][ni], 0, 0, 0);
        __syncthreads();
    }

#pragma unroll
    for (int mi = 0; mi < 2; ++mi) {
#pragma unroll
        for (int ni = 0; ni < 2; ++ni) {
            int ocol = tCol + wCol + ni * 16 + fr;
            if (ocol >= N) continue;
            float bv = bias ? bias[ocol] : 0.0f;
#pragma unroll
            for (int i = 0; i < 4; ++i) {
                int orow = tRow + wRow + mi * 16 + fg * 4 + i;
                float v = acc[mi][ni][i] + bv;
                if constexpr (EPI == 3) {
                    // scatter to head-major bf16 Q|K|Vt buffers
                    int bq = orow >> 10, tt = orow & 1023;
                    int sec = ocol / CDIM, rem = ocol - sec * CDIM;
                    int hh = rem >> 6, dd = rem & 63;
                    int bh = bq * NH + hh;
                    unsigned short* qb = (unsigned short*)out;
                    if (sec == 0)
                        qb[(size_t)(bh * T_SEQ + tt) * HDIM + dd] = f2bf(v * 0.125f);
                    else if (sec == 1)
                        qb[QKE + (size_t)(bh * T_SEQ + tt) * HDIM + dd] = f2bf(v);
                    else
                        qb[2 * (size_t)QKE + (size_t)(bh * HDIM + dd) * T_SEQ + tt] = f2bf(v);
                } else {
                    if (EPI == 1) {
                        float t = v;
                        v = 0.5f * t * (1.0f + tanhf(0.7978845608028654f *
                                                     (t + 0.044715f * t * t * t)));
                    }
                    size_t oidx = (size_t)orow * N + ocol;
                    if (EPI == 2) v += resid[oidx];
                    if constexpr (sizeof(OT) == 4) out[oidx] = v;
                    else                           out[oidx] = (OT)f2bf(v);
                }
            }
        }
    }
}

// ---------------------------------------------------------------------------
// Flash attention (bf16 MFMA). Grid: (16 q-tiles, 24 bh). 4 waves/block,
// each wave owns 16 q-rows. KV tiles of 64, causal; the FIRE bias (-1e30
// above the diagonal) doubles as the causal mask.
// Layouts: Qb/Kb [bh][t][64] bf16 (Q pre-scaled by 1/8), Vt [bh][64][t] bf16.
// ---------------------------------------------------------------------------
__global__ __launch_bounds__(256) void fattn_kernel(
    const unsigned short* __restrict__ qkvb,
    const float* __restrict__ bias,
    unsigned short* __restrict__ y)
{
    __shared__ unsigned short Ks[64][72];       // [j][d], +8 pad: 2-way banks only
    __shared__ unsigned short Vs[64][72];       // [d][j]
    __shared__ unsigned short Ps[4][16][72];    // per-wave P bounce [q][j]

    int tid = threadIdx.x;
    int lane = tid & 63, w = tid >> 6;
    int fr = lane & 15, fg = lane >> 4;
    int qt = (int)gridDim.x - 1 - (int)blockIdx.x;  // big tiles first
    int bh = blockIdx.y;
    int b  = bh / NH, h = bh % NH;

    const unsigned short* Qb = qkvb + (size_t)bh * T_SEQ * HDIM;
    const unsigned short* Kb = qkvb + QKE + (size_t)bh * T_SEQ * HDIM;
    const unsigned short* Vt = qkvb + 2 * (size_t)QKE + (size_t)bh * HDIM * T_SEQ;

    // Q fragments (A-operand), rows qt*64 + w*16 + fr
    int qrow = qt * 64 + w * 16 + fr;
    short8 qf[2];
#pragma unroll
    for (int ks = 0; ks < 2; ++ks)
        qf[ks] = *(const short8*)(Qb + (size_t)qrow * HDIM + ks * 32 + fg * 8);

    f32x4 o[4];
#pragma unroll
    for (int nf = 0; nf < 4; ++nf) o[nf] = (f32x4){0.f, 0.f, 0.f, 0.f};
    float m[4] = {-1e30f, -1e30f, -1e30f, -1e30f};
    float l[4] = {0.f, 0.f, 0.f, 0.f};

    int qbase = qt * 64 + w * 16 + fg * 4;  // + i

    for (int jt = 0; jt <= qt; ++jt) {
        __syncthreads();
        // stage K tile [j][d] and V tile [d][j] (both 16B coalesced)
#pragma unroll
        for (int rep = 0; rep < 2; ++rep) {
            int li = rep * 2048 + tid * 8;
            int r = li >> 6, c = li & 63;
            *(short8*)&Ks[r][c] = *(const short8*)(Kb + (size_t)(jt * 64 + r) * HDIM + c);
            *(short8*)&Vs[r][c] = *(const short8*)(Vt + (size_t)r * T_SEQ + jt * 64 + c);
        }
        __syncthreads();

        // S = Q K^T (+bias)
        f32x4 s[4];
#pragma unroll
        for (int nf = 0; nf < 4; ++nf) s[nf] = (f32x4){0.f, 0.f, 0.f, 0.f};
#pragma unroll
        for (int ks = 0; ks < 2; ++ks) {
#pragma unroll
            for (int nf = 0; nf < 4; ++nf) {
                short8 kf = *(const short8*)&Ks[nf * 16 + fr][ks * 32 + fg * 8];
                s[nf] = __builtin_amdgcn_mfma_f32_16x16x32_bf16(qf[ks], kf, s[nf], 0, 0, 0);
            }
        }
#pragma unroll
        for (int nf = 0; nf < 4; ++nf) {
            int j = jt * 64 + nf * 16 + fr;
#pragma unroll
            for (int i = 0; i < 4; ++i)
                s[nf][i] += bias[(size_t)(qbase + i) * T_SEQ + j];
        }

        // row max across the 16-lane group (rows live at (lane>>4)*4+i)
#pragma unroll
        for (int i = 0; i < 4; ++i) {
            float v = fmaxf(fmaxf(s[0][i], s[1][i]), fmaxf(s[2][i], s[3][i]));
            v = fmaxf(v, __shfl_xor(v, 1, 16));
            v = fmaxf(v, __shfl_xor(v, 2, 16));
            v = fmaxf(v, __shfl_xor(v, 4, 16));
            v = fmaxf(v, __shfl_xor(v, 8, 16));
            float mn = fmaxf(m[i], v);
            float alpha = __expf(m[i] - mn);
            m[i] = mn;
            l[i] *= alpha;
#pragma unroll
            for (int nf = 0; nf < 4; ++nf) o[nf][i] *= alpha;
        }

        // P = exp(S - m): accumulate row sums, bounce to LDS as bf16
        float rsum[4] = {0.f, 0.f, 0.f, 0.f};
#pragma unroll
        for (int nf = 0; nf < 4; ++nf) {
#pragma unroll
            for (int i = 0; i < 4; ++i) {
                float p = __expf(s[nf][i] - m[i]);
                rsum[i] += p;
                Ps[w][fg * 4 + i][nf * 16 + fr] = f2bf(p);
            }
        }
#pragma unroll
        for (int i = 0; i < 4; ++i) {
            float v = rsum[i];
            v += __shfl_xor(v, 1, 16);
            v += __shfl_xor(v, 2, 16);
            v += __shfl_xor(v, 4, 16);
            v += __shfl_xor(v, 8, 16);
            l[i] += v;
        }

        // O += P @ V   (P as A-operand from wave-local LDS, V^T as B-operand)
#pragma unroll
        for (int ks = 0; ks < 2; ++ks) {
            short8 pf = *(const short8*)&Ps[w][fr][ks * 32 + fg * 8];
#pragma unroll
            for (int nf = 0; nf < 4; ++nf) {
                short8 vf = *(const short8*)&Vs[nf * 16 + fr][ks * 32 + fg * 8];
                o[nf] = __builtin_amdgcn_mfma_f32_16x16x32_bf16(pf, vf, o[nf], 0, 0, 0);
            }
        }
    }

    // write y[b,t, h*64+d] bf16
#pragma unroll
    for (int nf = 0; nf < 4; ++nf) {
        int c = h * HDIM + nf * 16 + fr;
#pragma unroll
        for (int i = 0; i < 4; ++i) {
            float v = o[nf][i] / l[i];
            y[(size_t)(b * T_SEQ + qbase + i) * CDIM + c] = f2bf(v);
        }
    }
}

// ---------------------------------------------------------------------------
// kernel_launch
// ---------------------------------------------------------------------------
extern "C" void kernel_launch(void* const* d_in, const int* in_sizes, int n_in,
                              void* d_out, int out_size, void* d_ws, size_t ws_size,
                              hipStream_t stream)
{
    const int*   idx   = (const int*)  d_in[0];
    const float* wte   = (const float*)d_in[2];
    const float* log_c = (const float*)d_in[3];
    const float* v1w   = (const float*)d_in[4];
    const float* v1b   = (const float*)d_in[5];
    const float* v2w   = (const float*)d_in[6];
    const float* v2b   = (const float*)d_in[7];
    const float* v3w   = (const float*)d_in[8];
    const float* v3b   = (const float*)d_in[9];
    const float* ln1g  = (const float*)d_in[10];
    const float* ln1b  = (const float*)d_in[11];
    const float* attnw = (const float*)d_in[12];
    const float* attnb = (const float*)d_in[13];
    const float* projw = (const float*)d_in[14];
    const float* projb = (const float*)d_in[15];
    const float* ln2g  = (const float*)d_in[16];
    const float* ln2b  = (const float*)d_in[17];
    const float* fcw   = (const float*)d_in[18];
    const float* fcb   = (const float*)d_in[19];
    const float* fc2w  = (const float*)d_in[20];
    const float* fc2b  = (const float*)d_in[21];
    const float* lnfg  = (const float*)d_in[22];
    const float* lnfb  = (const float*)d_in[23];
    float* outp = (float*)d_out;

    // ---- workspace layout ----
    char* w = (char*)d_ws;
    float* bias          = (float*)w;          w += (size_t)T_SEQ * T_SEQ * 4;     // 4 MB
    float* x             = (float*)w;          w += (size_t)BROWS * CDIM * 4;      // 6.3 MB
    unsigned short* hbuf = (unsigned short*)w; w += (size_t)BROWS * CDIM * 2;      // 3.1 MB
    unsigned short* qkvb = (unsigned short*)w; w += (size_t)3 * QKE * 2;           // 9.4 MB
    unsigned short* ybuf = (unsigned short*)w; w += (size_t)BROWS * CDIM * 2;      // 3.1 MB
    unsigned short* gbuf = (unsigned short*)w; w += (size_t)BROWS * 4 * CDIM * 2;  // 12.6 MB

    fire_kernel<<<(T_SEQ * T_SEQ) / 256, 256, 0, stream>>>(
        log_c, v1w, v1b, v2w, v2b, v3w, v3b, bias);
    embed_kernel<<<BROWS, 256, 0, stream>>>(idx, wte, x);

    for (int l = 0; l < NLAYER; ++l) {
        ln_kernel<<<BROWS, 256, 0, stream>>>(x, ln1g + l * CDIM, ln1b + l * CDIM, hbuf);
        gemm_kernel<3, false, unsigned short><<<dim3(3 * CDIM / 64, BROWS / 64), 256, 0, stream>>>(
            hbuf, attnw + (size_t)l * CDIM * 3 * CDIM, attnb + (size_t)l * 3 * CDIM,
            nullptr, qkvb, BROWS, 3 * CDIM, CDIM);
        fattn_kernel<<<dim3(T_SEQ / 64, NBH), 256, 0, stream>>>(qkvb, bias, ybuf);
        gemm_kernel<2, false, float><<<dim3(CDIM / 64, BROWS / 64), 256, 0, stream>>>(
            ybuf, projw + (size_t)l * CDIM * CDIM, projb + (size_t)l * CDIM,
            x, x, BROWS, CDIM, CDIM);
        ln_kernel<<<BROWS, 256, 0, stream>>>(x, ln2g + l * CDIM, ln2b + l * CDIM, hbuf);
        gemm_kernel<1, false, unsigned short><<<dim3(4 * CDIM / 64, BROWS / 64), 256, 0, stream>>>(
            hbuf, fcw + (size_t)l * CDIM * 4 * CDIM, fcb + (size_t)l * 4 * CDIM,
            nullptr, gbuf, BROWS, 4 * CDIM, CDIM);
        gemm_kernel<2, false, float><<<dim3(CDIM / 64, BROWS / 64), 256, 0, stream>>>(
            gbuf, fc2w + (size_t)l * 4 * CDIM * CDIM, fc2b + (size_t)l * CDIM,
            x, x, BROWS, CDIM, 4 * CDIM);
    }

    ln_kernel<<<BROWS, 256, 0, stream>>>(x, lnfg, lnfb, hbuf);
    gemm_kernel<0, true, float><<<dim3((VOCAB + 63) / 64, BROWS / 64), 256, 0, stream>>>(
        hbuf, wte, nullptr, nullptr, outp, BROWS, VOCAB, CDIM);
}